// Round 5
// baseline (1310.786 us; speedup 1.0000x reference)
//
#include <hip/hip_runtime.h>
#include <hip/hip_bf16.h>
#include <cstdint>
#include <cstddef>

#define DEVI __device__ __forceinline__

typedef __attribute__((ext_vector_type(4))) float f32x4;
typedef __attribute__((ext_vector_type(8))) short s16x8;
typedef __attribute__((ext_vector_type(4))) short s16x4;

constexpr int TB = 16;         // batch
constexpr int TT = 2048;       // time
constexpr int TD = 512;        // model dim
constexpr int TDFF = 2048;     // ffn dim
constexpr int NTOK = TB * TT;  // 32768
constexpr int KW = 31;         // conv kernel width
constexpr int CH = 8192;       // M-chunk (4 whole batches)
constexpr int NCHUNK = NTOK / CH;
constexpr int CT = 8;          // conv: tokens per block

DEVI float b2f(unsigned short u) {
  union { float f; unsigned v; } x; x.v = ((unsigned)u) << 16; return x.f;
}
DEVI unsigned short f2bfb(float f) {
  __hip_bfloat16 h = __float2bfloat16(f);
  return __builtin_bit_cast(unsigned short, h);
}
DEVI float sigm(float x) { return 1.0f / (1.0f + __expf(-x)); }

DEVI void gload_lds16(const void* g, void* l) {
  __builtin_amdgcn_global_load_lds(
      (__attribute__((address_space(1))) unsigned int*)g,
      (__attribute__((address_space(3))) unsigned int*)l, 16, 0, 0);
}

DEVI f32x4 mfma_bf16(s16x8 a, s16x8 b, f32x4 c) {
  asm("v_mfma_f32_16x16x32_bf16 %0, %1, %2, %0" : "+v"(c) : "v"(a), "v"(b));
  return c;
}

// ---------------------------------------------------------------------------
// gemm256: 256x256 tile, BK=64, 512 thr (8 waves, 2Mx4N), phase-split schedule
// (T2 swizzle + K-tile-ahead burst prefetch + T5 setprio). C = A x Bw^T + bias.
// LDS 128KB: [mat][parity][half][128 rows][64 bf16], parity = kt&1.
// Swizzle: LDS linear dest (global_load_lds), inverse-swizzled global SOURCE,
// swizzle on ds_read: cb ^= (row&7)<<4  (involution; both-sides rule).
// Invariants: reads of parity p occur after vmcnt(0)+barrier draining p's
// stages; writes to parity p^1 occur after the barrier retiring its readers.
// ---------------------------------------------------------------------------
template<int EPI>
__global__ __launch_bounds__(512, 2)
void gemm256(const __hip_bfloat16* __restrict__ A, const __hip_bfloat16* __restrict__ Bw,
             const float* __restrict__ bias, const float* resin, float* resout,
             __hip_bfloat16* __restrict__ outbf, int N, int K, float rscale)
{
  __shared__ alignas(16) char ldsb[131072];
  const int tid = threadIdx.x;
  const int w = tid >> 6, l = tid & 63;
  const int row0 = blockIdx.x * 256, col0 = blockIdx.y * 256;
  const int wr = w >> 2, wc = w & 3;           // wave -> (2 row, 4 col) grid

  f32x4 acc[8][4];
#pragma unroll
  for (int m = 0; m < 8; ++m)
#pragma unroll
    for (int n = 0; n < 4; ++n) acc[m][n] = f32x4{0.f, 0.f, 0.f, 0.f};

  // staging constants: linear LDS half-tile offset o = j*8192 + w*1024 + l*16
  // -> row = j*64 + w*8 + (l>>3), cb = (l&7)*16; row&7 == l>>3.
  const int srow_base = w * 8 + (l >> 3);
  const int scbs = ((l & 7) * 16) ^ ((l >> 3) << 4);   // inverse-swizzled src col byte

  auto stage_kt = [&](int kts) {
    const int par = kts & 1;
    const int k0e = kts * 64 + (scbs >> 1);
#pragma unroll
    for (int ht = 0; ht < 4; ++ht) {
      const int mat = ht >> 1, hh = ht & 1;
      const __hip_bfloat16* src = mat ? Bw : A;
      const int t0 = mat ? col0 : row0;
      const int lbase = mat * 65536 + par * 32768 + hh * 16384 + w * 1024;
#pragma unroll
      for (int j = 0; j < 2; ++j)
        gload_lds16(src + (size_t)(t0 + hh * 128 + srow_base + j * 64) * K + k0e,
                    ldsb + lbase + j * 8192);
    }
  };

  // prologue: K-tile 0 into parity 0
  stage_kt(0);
  asm volatile("s_waitcnt vmcnt(0)" ::: "memory");
  asm volatile("s_barrier" ::: "memory");

  const int nkt = K >> 6;
  const int lk = (l >> 4) * 16, al = l & 15, bro = (wc & 1) * 64;

#define G256_PH(Q)                                                              \
  do {                                                                          \
    constexpr int mh = (Q) >> 1, nh = (Q) & 1;                                  \
    s16x8 af[2][4], bq[2][2];                                                   \
    _Pragma("unroll") for (int ks = 0; ks < 2; ++ks) {                          \
      _Pragma("unroll") for (int mm = 0; mm < 4; ++mm) {                        \
        const int ar = (mh * 4 + mm) * 16 + al;                                 \
        af[ks][mm] = *(const s16x8*)(ldsb + abase + ar * 128 +                  \
                                     ((ks * 64 + lk) ^ ((ar & 7) << 4)));       \
      }                                                                         \
      _Pragma("unroll") for (int nn = 0; nn < 2; ++nn) {                        \
        const int br = bro + (nh * 2 + nn) * 16 + al;                           \
        bq[ks][nn] = *(const s16x8*)(ldsb + bbase + br * 128 +                  \
                                     ((ks * 64 + lk) ^ ((br & 7) << 4)));       \
      }                                                                         \
    }                                                                           \
    if ((Q) == 0 && kt + 1 < nkt) stage_kt(kt + 1);                             \
    asm volatile("s_barrier" ::: "memory");                                     \
    __builtin_amdgcn_s_setprio(1);                                              \
    _Pragma("unroll") for (int ks = 0; ks < 2; ++ks)                            \
      _Pragma("unroll") for (int mm = 0; mm < 4; ++mm)                          \
        _Pragma("unroll") for (int nn = 0; nn < 2; ++nn)                        \
          acc[mh * 4 + mm][nh * 2 + nn] = mfma_bf16(                            \
              af[ks][mm], bq[ks][nn], acc[mh * 4 + mm][nh * 2 + nn]);           \
    __builtin_amdgcn_s_setprio(0);                                              \
    if ((Q) == 3) asm volatile("s_waitcnt vmcnt(0)" ::: "memory");              \
    asm volatile("s_barrier" ::: "memory");                                     \
  } while (0)

  for (int kt = 0; kt < nkt; ++kt) {
    const int abase = (kt & 1) * 32768 + wr * 16384;
    const int bbase = 65536 + (kt & 1) * 32768 + (wc >> 1) * 16384;
    G256_PH(0); G256_PH(1); G256_PH(2); G256_PH(3);
  }
#undef G256_PH

  asm volatile("s_nop 7\n\ts_nop 7");   // MFMA->VALU read hazard guard

#pragma unroll
  for (int n = 0; n < 4; ++n) {
    const int gcol = col0 + wc * 64 + n * 16 + al;
    const float bv = bias[gcol];
#pragma unroll
    for (int m = 0; m < 8; ++m) {
      const int grow0 = row0 + wr * 128 + m * 16 + (l >> 4) * 4;
#pragma unroll
      for (int r = 0; r < 4; ++r) {
        const size_t idx = (size_t)(grow0 + r) * N + gcol;
        const float v = acc[m][n][r] + bv;
        if constexpr (EPI == 0) {
          outbf[idx] = __float2bfloat16(v);
        } else if constexpr (EPI == 1) {
          outbf[idx] = __float2bfloat16(v * sigm(v));
        } else {
          resout[idx] = resin[idx] + rscale * v;
        }
      }
    }
  }
}

// ---------------------------------------------------------------------------
// 128x128 m97-structure GEMM (kept for the N=512 chunked GEMMs). No swizzle.
// ---------------------------------------------------------------------------
template<int EPI>
__global__ __launch_bounds__(256)
void gemm_bt(const __hip_bfloat16* __restrict__ A, const __hip_bfloat16* __restrict__ Bw,
             const float* __restrict__ bias, const float* resin, float* resout,
             __hip_bfloat16* __restrict__ outbf, int N, int K, float rscale)
{
  __shared__ alignas(16) short lds[2 * 128 * 64];
  short* As = lds;
  short* Bs = lds + 128 * 64;

  const int tid = threadIdx.x;
  const int w = tid >> 6, l = tid & 63;
  const int row0 = blockIdx.x * 128;
  const int col0 = blockIdx.y * 128;

  const int srow = w * 8 + (l >> 3);
  const int scol = (l & 7) * 8;

  f32x4 acc[4][4];
#pragma unroll
  for (int m = 0; m < 4; ++m)
#pragma unroll
    for (int n = 0; n < 4; ++n)
      acc[m][n] = f32x4{0.f, 0.f, 0.f, 0.f};

  const int wr = (w >> 1) * 64, wc = (w & 1) * 64;

  for (int k0 = 0; k0 < K; k0 += 64) {
    __syncthreads();
#pragma unroll
    for (int it = 0; it < 4; ++it) {
      gload_lds16(A  + (size_t)(row0 + it * 32 + srow) * K + k0 + scol,
                  (char*)As + (it * 32 + w * 8) * 128);
      gload_lds16(Bw + (size_t)(col0 + it * 32 + srow) * K + k0 + scol,
                  (char*)Bs + (it * 32 + w * 8) * 128);
    }
    __syncthreads();
#pragma unroll
    for (int ks = 0; ks < 2; ++ks) {
      const int ko = ks * 64 + (l >> 4) * 16;
      s16x8 af[4], bfr[4];
#pragma unroll
      for (int m = 0; m < 4; ++m)
        af[m] = *(const s16x8*)((const char*)As + (wr + m * 16 + (l & 15)) * 128 + ko);
#pragma unroll
      for (int n = 0; n < 4; ++n)
        bfr[n] = *(const s16x8*)((const char*)Bs + (wc + n * 16 + (l & 15)) * 128 + ko);
#pragma unroll
      for (int m = 0; m < 4; ++m)
#pragma unroll
        for (int n = 0; n < 4; ++n)
          acc[m][n] = mfma_bf16(af[m], bfr[n], acc[m][n]);
    }
  }

  asm volatile("s_nop 7\n\ts_nop 7");

#pragma unroll
  for (int n = 0; n < 4; ++n) {
    const int gcol = col0 + wc + n * 16 + (l & 15);
    const float bv = bias[gcol];
#pragma unroll
    for (int m = 0; m < 4; ++m) {
      const int grow0 = row0 + wr + m * 16 + (l >> 4) * 4;
#pragma unroll
      for (int r = 0; r < 4; ++r) {
        const size_t idx = (size_t)(grow0 + r) * N + gcol;
        const float v = acc[m][n][r] + bv;
        if constexpr (EPI == 0) {
          outbf[idx] = __float2bfloat16(v);
        } else if constexpr (EPI == 1) {
          outbf[idx] = __float2bfloat16(v * sigm(v));
        } else {
          resout[idx] = resin[idx] + rscale * v;
        }
      }
    }
  }
}

// ---------------------------------------------------------------------------
// LayerNorm over D=512. One wave per token, 4 tokens/block.
// ---------------------------------------------------------------------------
template<int OUTF32>
__global__ __launch_bounds__(256)
void ln_k(const float* __restrict__ x, const float* __restrict__ g,
          const float* __restrict__ b, void* __restrict__ outp)
{
  const int w = threadIdx.x >> 6, l = threadIdx.x & 63;
  const size_t tok = (size_t)blockIdx.x * 4 + w;
  const float4* xr = (const float4*)(x + tok * TD);
  const float4 v0 = xr[l], v1 = xr[64 + l];
  float s = v0.x + v0.y + v0.z + v0.w + v1.x + v1.y + v1.z + v1.w;
  float q = v0.x * v0.x + v0.y * v0.y + v0.z * v0.z + v0.w * v0.w
          + v1.x * v1.x + v1.y * v1.y + v1.z * v1.z + v1.w * v1.w;
#pragma unroll
  for (int o = 32; o > 0; o >>= 1) { s += __shfl_xor(s, o); q += __shfl_xor(q, o); }
  const float mean = s * (1.f / TD);
  const float rs = rsqrtf(q * (1.f / TD) - mean * mean + 1e-5f);
  const float4 g0 = ((const float4*)g)[l], g1 = ((const float4*)g)[64 + l];
  const float4 b0 = ((const float4*)b)[l], b1 = ((const float4*)b)[64 + l];
  const float o0 = (v0.x - mean) * rs * g0.x + b0.x;
  const float o1 = (v0.y - mean) * rs * g0.y + b0.y;
  const float o2 = (v0.z - mean) * rs * g0.z + b0.z;
  const float o3 = (v0.w - mean) * rs * g0.w + b0.w;
  const float o4 = (v1.x - mean) * rs * g1.x + b1.x;
  const float o5 = (v1.y - mean) * rs * g1.y + b1.y;
  const float o6 = (v1.z - mean) * rs * g1.z + b1.z;
  const float o7 = (v1.w - mean) * rs * g1.w + b1.w;
  if constexpr (OUTF32) {
    float4* out = (float4*)outp + tok * 128;
    out[l]      = make_float4(o0, o1, o2, o3);
    out[64 + l] = make_float4(o4, o5, o6, o7);
  } else {
    s16x4 p0{(short)f2bfb(o0), (short)f2bfb(o1), (short)f2bfb(o2), (short)f2bfb(o3)};
    s16x4 p1{(short)f2bfb(o4), (short)f2bfb(o5), (short)f2bfb(o6), (short)f2bfb(o7)};
    ((s16x4*)outp)[tok * 128 + l]      = p0;
    ((s16x4*)outp)[tok * 128 + 64 + l] = p1;
  }
}

// ---------------------------------------------------------------------------
// Hydra pass1 (per M-chunk of 4 batches): qn = q/|q|; kvpart = sum (k/|k|)*v.
// ---------------------------------------------------------------------------
__global__ __launch_bounds__(256)
void hydra_pass1(const __hip_bfloat16* __restrict__ qkv,
                 __hip_bfloat16* __restrict__ qn,
                 float* __restrict__ kvpart, int b0)
{
  const int bl = blockIdx.x, ch = blockIdx.y;
  const int w = threadIdx.x >> 6, l = threadIdx.x & 63;
  float kvp[8] = {0.f, 0.f, 0.f, 0.f, 0.f, 0.f, 0.f, 0.f};
  __shared__ float part[4][512];

  for (int it = 0; it < 16; ++it) {
    const int t = ch * 64 + w * 16 + it;
    const short* row = (const short*)qkv + ((size_t)bl * TT + t) * (3 * TD);
    const s16x8 q8 = *(const s16x8*)(row + 8 * l);
    const s16x8 k8 = *(const s16x8*)(row + TD + 8 * l);
    const s16x8 v8 = *(const s16x8*)(row + 2 * TD + 8 * l);
    float qf[8], kf[8], vf[8];
    float sq = 0.f, sk = 0.f;
#pragma unroll
    for (int j = 0; j < 8; ++j) {
      qf[j] = b2f((unsigned short)q8[j]); sq += qf[j] * qf[j];
      kf[j] = b2f((unsigned short)k8[j]); sk += kf[j] * kf[j];
      vf[j] = b2f((unsigned short)v8[j]);
    }
#pragma unroll
    for (int o = 32; o > 0; o >>= 1) { sq += __shfl_xor(sq, o); sk += __shfl_xor(sk, o); }
    const float rq = rsqrtf(sq), rk = rsqrtf(sk);
    s16x8 r;
#pragma unroll
    for (int j = 0; j < 8; ++j) {
      r[j] = (short)f2bfb(qf[j] * rq);
      kvp[j] += kf[j] * rk * vf[j];
    }
    *(s16x8*)((short*)qn + ((size_t)bl * TT + t) * TD + 8 * l) = r;
  }
#pragma unroll
  for (int j = 0; j < 8; ++j) part[w][8 * l + j] = kvp[j];
  __syncthreads();
#pragma unroll
  for (int hh = 0; hh < 2; ++hh) {
    const int d = threadIdx.x + hh * 256;
    kvpart[((size_t)(b0 + bl) * 32 + ch) * TD + d]
        = part[0][d] + part[1][d] + part[2][d] + part[3][d];
  }
}

__global__ __launch_bounds__(256)
void kv_reduce(const float* __restrict__ kvpart, float* __restrict__ kv)
{
  const int i = blockIdx.x * 256 + threadIdx.x;
  const int b = i >> 9, d = i & 511;
  float s = 0.f;
#pragma unroll
  for (int ch = 0; ch < 32; ++ch) s += kvpart[((size_t)b * 32 + ch) * TD + d];
  kv[i] = s;
}

__global__ __launch_bounds__(256)
void qscale_k(__hip_bfloat16* qn, const float* __restrict__ kv)
{
  const size_t i = ((size_t)blockIdx.x * 256 + threadIdx.x) * 8;
  const size_t tok = i >> 9;
  const int d = (int)(i & 511);
  const int b = (int)(tok >> 11);
  const s16x8 v = *(const s16x8*)((const short*)qn + i);
  const float4 k0 = *(const float4*)(kv + b * 512 + d);
  const float4 k1 = *(const float4*)(kv + b * 512 + d + 4);
  s16x8 r;
  r[0] = (short)f2bfb(b2f((unsigned short)v[0]) * k0.x);
  r[1] = (short)f2bfb(b2f((unsigned short)v[1]) * k0.y);
  r[2] = (short)f2bfb(b2f((unsigned short)v[2]) * k0.z);
  r[3] = (short)f2bfb(b2f((unsigned short)v[3]) * k0.w);
  r[4] = (short)f2bfb(b2f((unsigned short)v[4]) * k1.x);
  r[5] = (short)f2bfb(b2f((unsigned short)v[5]) * k1.y);
  r[6] = (short)f2bfb(b2f((unsigned short)v[6]) * k1.z);
  r[7] = (short)f2bfb(b2f((unsigned short)v[7]) * k1.w);
  *(s16x8*)((short*)qn + i) = r;
}

__global__ __launch_bounds__(256)
void glu_k(const __hip_bfloat16* __restrict__ c, __hip_bfloat16* __restrict__ out)
{
  const size_t i = ((size_t)blockIdx.x * 256 + threadIdx.x) * 8;
  const size_t tok = i >> 9;
  const int d = (int)(i & 511);
  const short* row = (const short*)c + tok * 1024;
  const s16x8 a8 = *(const s16x8*)(row + d);
  const s16x8 g8 = *(const s16x8*)(row + 512 + d);
  s16x8 r;
#pragma unroll
  for (int j = 0; j < 8; ++j) {
    const float a = b2f((unsigned short)a8[j]);
    const float g = b2f((unsigned short)g8[j]);
    r[j] = (short)f2bfb(a * sigm(g));
  }
  *(s16x8*)((short*)out + i) = r;
}

__global__ __launch_bounds__(256)
void dwt_k(const float* __restrict__ dww, float* __restrict__ dwt)
{
  const int i = blockIdx.x * 256 + threadIdx.x;
  if (i >= KW * TD) return;
  const int j = i / TD, d = i % TD;
  dwt[i] = dww[d * KW + j];
}

// depthwise conv + bias + LN + swish (v3: 512 thr, 1 ch/thread, 4 FMA chains)
__global__ __launch_bounds__(512)
void conv_ln_swish3(const __hip_bfloat16* __restrict__ gin, const float* __restrict__ dwt,
                    const float* __restrict__ dwb, const float* __restrict__ lg,
                    const float* __restrict__ lb, __hip_bfloat16* __restrict__ out)
{
  const int b  = blockIdx.x / (TT / CT);
  const int t0 = (blockIdx.x % (TT / CT)) * CT;
  const int d  = threadIdx.x;
  const int w = threadIdx.x >> 6, l = threadIdx.x & 63;

  float wreg[KW];
#pragma unroll
  for (int j = 0; j < KW; ++j) wreg[j] = dwt[j * TD + d];

  const unsigned short* base = (const unsigned short*)gin + (size_t)b * TT * TD + d;
  float xv[CT + KW - 1];
#pragma unroll
  for (int r = 0; r < CT + KW - 1; ++r) {
    const int tt = t0 + r - 15;
    xv[r] = (tt >= 0 && tt < TT) ? b2f(base[(size_t)tt * TD]) : 0.f;
  }

  const float bv = dwb[d];
  float a[CT];
#pragma unroll
  for (int t = 0; t < CT; ++t) {
    float p0 = bv, p1 = 0.f, p2 = 0.f, p3 = 0.f;
#pragma unroll
    for (int j = 0; j < 8; ++j) {
      p0 += xv[t + j] * wreg[j];
      p1 += xv[t + 8 + j] * wreg[8 + j];
      p2 += xv[t + 16 + j] * wreg[16 + j];
      if (j < 7) p3 += xv[t + 24 + j] * wreg[24 + j];
    }
    a[t] = (p0 + p1) + (p2 + p3);
  }

  __shared__ float red[2][8][CT];
#pragma unroll
  for (int t = 0; t < CT; ++t) {
    float ps = a[t], pq = a[t] * a[t];
#pragma unroll
    for (int o = 32; o > 0; o >>= 1) { ps += __shfl_xor(ps, o); pq += __shfl_xor(pq, o); }
    if (l == 0) { red[0][w][t] = ps; red[1][w][t] = pq; }
  }
  __syncthreads();
  const float gv = lg[d], bbv = lb[d];
#pragma unroll
  for (int t = 0; t < CT; ++t) {
    float s = 0.f, q = 0.f;
#pragma unroll
    for (int ww = 0; ww < 8; ++ww) { s += red[0][ww][t]; q += red[1][ww][t]; }
    const float mean = s * (1.f / TD);
    const float rs = rsqrtf(q * (1.f / TD) - mean * mean + 1e-5f);
    const float y = (a[t] - mean) * rs * gv + bbv;
    out[((size_t)b * TT + t0 + t) * TD + d] = __float2bfloat16(y * sigm(y));
  }
}

__global__ __launch_bounds__(256)
void cast8_k(const float* __restrict__ in, __hip_bfloat16* __restrict__ out, int n8)
{
  const int i = blockIdx.x * 256 + threadIdx.x;
  if (i >= n8) return;
  const float4 a = ((const float4*)in)[2 * i];
  const float4 b = ((const float4*)in)[2 * i + 1];
  s16x8 r;
  r[0] = (short)f2bfb(a.x); r[1] = (short)f2bfb(a.y);
  r[2] = (short)f2bfb(a.z); r[3] = (short)f2bfb(a.w);
  r[4] = (short)f2bfb(b.x); r[5] = (short)f2bfb(b.y);
  r[6] = (short)f2bfb(b.z); r[7] = (short)f2bfb(b.w);
  ((s16x8*)out)[i] = r;
}

extern "C" void kernel_launch(void* const* d_in, const int* in_sizes, int n_in,
                              void* d_out, int out_size, void* d_ws, size_t ws_size,
                              hipStream_t stream)
{
  const float* x      = (const float*)d_in[0];
  const float* ln1_g  = (const float*)d_in[1];
  const float* ln1_b  = (const float*)d_in[2];
  const float* ff1_w1 = (const float*)d_in[3];
  const float* ff1_b1 = (const float*)d_in[4];
  const float* ff1_w2 = (const float*)d_in[5];
  const float* ff1_b2 = (const float*)d_in[6];
  const float* lna_g  = (const float*)d_in[7];
  const float* lna_b  = (const float*)d_in[8];
  const float* qkv_w  = (const float*)d_in[9];
  const float* qkv_b  = (const float*)d_in[10];
  const float* aow    = (const float*)d_in[11];
  const float* aob    = (const float*)d_in[12];
  const float* lnc_g  = (const float*)d_in[13];
  const float* lnc_b  = (const float*)d_in[14];
  const float* pw1_w  = (const float*)d_in[15];
  const float* pw1_b  = (const float*)d_in[16];
  const float* dw_w   = (const float*)d_in[17];
  const float* dw_b   = (const float*)d_in[18];
  const float* lncn_g = (const float*)d_in[19];
  const float* lncn_b = (const float*)d_in[20];
  const float* pw2_w  = (const float*)d_in[21];
  const float* pw2_b  = (const float*)d_in[22];
  const float* ln2_g  = (const float*)d_in[23];
  const float* ln2_b  = (const float*)d_in[24];
  const float* ff2_w1 = (const float*)d_in[25];
  const float* ff2_b1 = (const float*)d_in[26];
  const float* ff2_w2 = (const float*)d_in[27];
  const float* ff2_b2 = (const float*)d_in[28];
  const float* lno_g  = (const float*)d_in[29];
  const float* lno_b  = (const float*)d_in[30];
  (void)in_sizes; (void)n_in; (void)out_size;

  float* res = (float*)d_out;

  char* ws = (char*)d_ws;
  size_t off = 0;
  auto alloc = [&](size_t bytes) {
    char* p = ws + off;
    off = (off + bytes + 255) & ~(size_t)255;
    return p;
  };

  __hip_bfloat16* wff1a = (__hip_bfloat16*)alloc((size_t)TDFF * TD * 2);
  __hip_bfloat16* wff1b = (__hip_bfloat16*)alloc((size_t)TD * TDFF * 2);
  __hip_bfloat16* wqkv  = (__hip_bfloat16*)alloc((size_t)3 * TD * TD * 2);
  __hip_bfloat16* wao   = (__hip_bfloat16*)alloc((size_t)TD * TD * 2);
  __hip_bfloat16* wpw1  = (__hip_bfloat16*)alloc((size_t)2 * TD * TD * 2);
  __hip_bfloat16* wpw2  = (__hip_bfloat16*)alloc((size_t)TD * TD * 2);
  __hip_bfloat16* wff2a = (__hip_bfloat16*)alloc((size_t)TDFF * TD * 2);
  __hip_bfloat16* wff2b = (__hip_bfloat16*)alloc((size_t)TD * TDFF * 2);
  __hip_bfloat16* h     = (__hip_bfloat16*)alloc((size_t)NTOK * TD * 2);
  __hip_bfloat16* big   = (__hip_bfloat16*)alloc((size_t)CH * TDFF * 2);
  float*          kv    = (float*)alloc((size_t)TB * TD * 4);
  float*          kvp   = (float*)alloc((size_t)TB * 32 * TD * 4);
  float*          dwt   = (float*)alloc((size_t)KW * TD * 4);

  if (ws_size < off) return;

  const dim3 blk(256), blk512(512);
  const int M = NTOK;

  auto cast = [&](const float* src, __hip_bfloat16* dst, int n) {
    cast8_k<<<(n / 8 + 255) / 256, blk, 0, stream>>>(src, dst, n / 8);
  };
  cast(ff1_w1, wff1a, TDFF * TD);
  cast(ff1_w2, wff1b, TD * TDFF);
  cast(qkv_w,  wqkv,  3 * TD * TD);
  cast(aow,    wao,   TD * TD);
  cast(pw1_w,  wpw1,  2 * TD * TD);
  cast(pw2_w,  wpw2,  TD * TD);
  cast(ff2_w1, wff2a, TDFF * TD);
  cast(ff2_w2, wff2b, TD * TDFF);
  dwt_k<<<(KW * TD + 255) / 256, blk, 0, stream>>>(dw_w, dwt);

  // ---- FF1 (half-step): res = x + 0.5*ffn(ln1(x)) ----
  ln_k<0><<<M / 4, blk, 0, stream>>>(x, ln1_g, ln1_b, h);
  for (int c = 0; c < NCHUNK; ++c) {
    const size_t o5 = (size_t)c * CH * TD;
    gemm256<1><<<dim3(CH / 256, TDFF / 256), blk512, 0, stream>>>(
        h + o5, wff1a, ff1_b1, nullptr, nullptr, big, TDFF, TD, 0.f);
    gemm_bt<2><<<dim3(CH / 128, TD / 128), blk, 0, stream>>>(
        big, wff1b, ff1_b2, x + o5, res + o5, nullptr, TD, TDFF, 0.5f);
  }

  // ---- Hydra attention ----
  ln_k<0><<<M / 4, blk, 0, stream>>>(res, lna_g, lna_b, h);
  for (int c = 0; c < NCHUNK; ++c) {
    const size_t o5 = (size_t)c * CH * TD;
    gemm256<0><<<dim3(CH / 256, 3 * TD / 256), blk512, 0, stream>>>(
        h + o5, wqkv, qkv_b, nullptr, nullptr, big, 3 * TD, TD, 0.f);
    hydra_pass1<<<dim3(CH / TT, 32), blk, 0, stream>>>(big, h + o5, kvp, c * (CH / TT));
  }
  kv_reduce<<<(TB * TD) / 256, blk, 0, stream>>>(kvp, kv);
  qscale_k<<<(M * (TD / 8)) / 256, blk, 0, stream>>>(h, kv);
  gemm256<2><<<dim3(M / 256, TD / 256), blk512, 0, stream>>>(
      h, wao, aob, res, res, nullptr, TD, TD, 1.f);

  // ---- Conv module ----
  ln_k<0><<<M / 4, blk, 0, stream>>>(res, lnc_g, lnc_b, h);
  for (int c = 0; c < NCHUNK; ++c) {
    const size_t o5 = (size_t)c * CH * TD;
    gemm256<0><<<dim3(CH / 256, 2 * TD / 256), blk512, 0, stream>>>(
        h + o5, wpw1, pw1_b, nullptr, nullptr, big, 2 * TD, TD, 0.f);
    glu_k<<<(CH * (TD / 8)) / 256, blk, 0, stream>>>(big, h + o5);
  }
  conv_ln_swish3<<<TB * (TT / CT), blk512, 0, stream>>>(h, dwt, dw_b, lncn_g, lncn_b, big);
  gemm256<2><<<dim3(M / 256, TD / 256), blk512, 0, stream>>>(
      big, wpw2, pw2_b, res, res, nullptr, TD, TD, 1.f);

  // ---- FF2 (half-step) ----
  ln_k<0><<<M / 4, blk, 0, stream>>>(res, ln2_g, ln2_b, h);
  for (int c = 0; c < NCHUNK; ++c) {
    const size_t o5 = (size_t)c * CH * TD;
    gemm256<1><<<dim3(CH / 256, TDFF / 256), blk512, 0, stream>>>(
        h + o5, wff2a, ff2_b1, nullptr, nullptr, big, TDFF, TD, 0.f);
    gemm_bt<2><<<dim3(CH / 128, TD / 128), blk, 0, stream>>>(
        big, wff2b, ff2_b2, res + o5, res + o5, nullptr, TD, TDFF, 0.5f);
  }

  // ---- final LN (in-place on d_out) ----
  ln_k<1><<<M / 4, blk, 0, stream>>>(res, lno_g, lno_b, res);
}

// Round 6
// 1118.662 us; speedup vs baseline: 1.1717x; 1.1717x over previous
//
#include <hip/hip_runtime.h>
#include <hip/hip_bf16.h>
#include <cstdint>
#include <cstddef>

#define DEVI __device__ __forceinline__

typedef __attribute__((ext_vector_type(4))) float f32x4;
typedef __attribute__((ext_vector_type(8))) short s16x8;
typedef __attribute__((ext_vector_type(4))) short s16x4;

constexpr int TB = 16;         // batch
constexpr int TT = 2048;       // time
constexpr int TD = 512;        // model dim
constexpr int TDFF = 2048;     // ffn dim
constexpr int NTOK = TB * TT;  // 32768
constexpr int KW = 31;         // conv kernel width
constexpr int CH = 8192;       // M-chunk (4 whole batches)
constexpr int NCHUNK = NTOK / CH;
constexpr int CT = 16;         // conv: tokens per block

DEVI float b2f(unsigned short u) {
  union { float f; unsigned v; } x; x.v = ((unsigned)u) << 16; return x.f;
}
DEVI unsigned short f2bfb(float f) {
  __hip_bfloat16 h = __float2bfloat16(f);
  return __builtin_bit_cast(unsigned short, h);
}
DEVI float sigm(float x) { return 1.0f / (1.0f + __expf(-x)); }

DEVI void gload_lds16(const void* g, void* l) {
  __builtin_amdgcn_global_load_lds(
      (__attribute__((address_space(1))) unsigned int*)g,
      (__attribute__((address_space(3))) unsigned int*)l, 16, 0, 0);
}

DEVI f32x4 mfma_bf16(s16x8 a, s16x8 b, f32x4 c) {
  asm("v_mfma_f32_16x16x32_bf16 %0, %1, %2, %0" : "+v"(c) : "v"(a), "v"(b));
  return c;
}

// ---------------------------------------------------------------------------
// GEMM: C(Mrows,N) = A(.,K) x B(N,K)^T + bias  (A,B bf16 row-major)
// EPI 0: out = bf16(acc+bias)
// EPI 1: out = bf16(swish(acc+bias))
// EPI 2: resout = resin + rscale*(acc+bias)   (f32; resin may alias resout)
// 128x128 tile, BK=64, 256 thr (4 waves 2x2), global_load_lds width-16 staging.
// SWAPPED-OPERAND mfma(b,a): lane holds row = Ablk + m*16 + (l&15) fixed,
// reg r = 4 consecutive C-cols at Bblk + n*16 + (l>>4)*4 -> vectorized stores.
// ---------------------------------------------------------------------------
template<int EPI>
__global__ __launch_bounds__(256)
void gemm_bt(const __hip_bfloat16* __restrict__ A, const __hip_bfloat16* __restrict__ Bw,
             const float* __restrict__ bias, const float* resin, float* resout,
             __hip_bfloat16* __restrict__ outbf, int N, int K, float rscale)
{
  __shared__ alignas(16) short lds[2 * 128 * 64];   // A tile then B tile, 16KB each
  short* As = lds;
  short* Bs = lds + 128 * 64;

  const int tid = threadIdx.x;
  const int w = tid >> 6, l = tid & 63;
  const int row0 = blockIdx.x * 128;
  const int col0 = blockIdx.y * 128;

  // staging: each wave's 64 lanes write LDS base + lane*16B -> 8 rows of 64 bf16
  const int srow = w * 8 + (l >> 3);
  const int scol = (l & 7) * 8;

  f32x4 acc[4][4];
#pragma unroll
  for (int m = 0; m < 4; ++m)
#pragma unroll
    for (int n = 0; n < 4; ++n)
      acc[m][n] = f32x4{0.f, 0.f, 0.f, 0.f};

  const int wr = (w >> 1) * 64, wc = (w & 1) * 64;

  for (int k0 = 0; k0 < K; k0 += 64) {
    __syncthreads();   // prior-iter ds_reads done before overwrite
#pragma unroll
    for (int it = 0; it < 4; ++it) {
      gload_lds16(A  + (size_t)(row0 + it * 32 + srow) * K + k0 + scol,
                  (char*)As + (it * 32 + w * 8) * 128);
      gload_lds16(Bw + (size_t)(col0 + it * 32 + srow) * K + k0 + scol,
                  (char*)Bs + (it * 32 + w * 8) * 128);
    }
    __syncthreads();   // vmcnt(0)+lgkmcnt(0) drained before barrier -> LDS visible
#pragma unroll
    for (int ks = 0; ks < 2; ++ks) {
      const int ko = ks * 64 + (l >> 4) * 16;   // byte offset in 128B row
      s16x8 af[4], bfr[4];
#pragma unroll
      for (int m = 0; m < 4; ++m)
        af[m] = *(const s16x8*)((const char*)As + (wr + m * 16 + (l & 15)) * 128 + ko);
#pragma unroll
      for (int n = 0; n < 4; ++n)
        bfr[n] = *(const s16x8*)((const char*)Bs + (wc + n * 16 + (l & 15)) * 128 + ko);
#pragma unroll
      for (int m = 0; m < 4; ++m)
#pragma unroll
        for (int n = 0; n < 4; ++n)
          acc[m][n] = mfma_bf16(bfr[n], af[m], acc[m][n]);   // swapped: C^T frag
    }
  }

  asm volatile("s_nop 7\n\ts_nop 7");   // MFMA->VALU read hazard guard

#pragma unroll
  for (int m = 0; m < 4; ++m) {
    const int grow = row0 + wr + m * 16 + (l & 15);
#pragma unroll
    for (int n = 0; n < 4; ++n) {
      const int gcol0 = col0 + wc + n * 16 + (l >> 4) * 4;
      const size_t idx = (size_t)grow * N + gcol0;
      const float4 bv = *(const float4*)(bias + gcol0);
      float vx = acc[m][n][0] + bv.x;
      float vy = acc[m][n][1] + bv.y;
      float vz = acc[m][n][2] + bv.z;
      float vw = acc[m][n][3] + bv.w;
      if constexpr (EPI == 0) {
        s16x4 p{(short)f2bfb(vx), (short)f2bfb(vy), (short)f2bfb(vz), (short)f2bfb(vw)};
        *(s16x4*)(outbf + idx) = p;
      } else if constexpr (EPI == 1) {
        vx *= sigm(vx); vy *= sigm(vy); vz *= sigm(vz); vw *= sigm(vw);
        s16x4 p{(short)f2bfb(vx), (short)f2bfb(vy), (short)f2bfb(vz), (short)f2bfb(vw)};
        *(s16x4*)(outbf + idx) = p;
      } else {
        const float4 rv = *(const float4*)(resin + idx);
        *(float4*)(resout + idx) = make_float4(rv.x + rscale * vx, rv.y + rscale * vy,
                                               rv.z + rscale * vz, rv.w + rscale * vw);
      }
    }
  }
}

// ---------------------------------------------------------------------------
// LayerNorm over D=512. One wave per token, 4 tokens/block.
// ---------------------------------------------------------------------------
template<int OUTF32>
__global__ __launch_bounds__(256)
void ln_k(const float* __restrict__ x, const float* __restrict__ g,
          const float* __restrict__ b, void* __restrict__ outp)
{
  const int w = threadIdx.x >> 6, l = threadIdx.x & 63;
  const size_t tok = (size_t)blockIdx.x * 4 + w;
  const float4* xr = (const float4*)(x + tok * TD);
  const float4 v0 = xr[l], v1 = xr[64 + l];
  float s = v0.x + v0.y + v0.z + v0.w + v1.x + v1.y + v1.z + v1.w;
  float q = v0.x * v0.x + v0.y * v0.y + v0.z * v0.z + v0.w * v0.w
          + v1.x * v1.x + v1.y * v1.y + v1.z * v1.z + v1.w * v1.w;
#pragma unroll
  for (int o = 32; o > 0; o >>= 1) { s += __shfl_xor(s, o); q += __shfl_xor(q, o); }
  const float mean = s * (1.f / TD);
  const float rs = rsqrtf(q * (1.f / TD) - mean * mean + 1e-5f);
  const float4 g0 = ((const float4*)g)[l], g1 = ((const float4*)g)[64 + l];
  const float4 b0 = ((const float4*)b)[l], b1 = ((const float4*)b)[64 + l];
  const float o0 = (v0.x - mean) * rs * g0.x + b0.x;
  const float o1 = (v0.y - mean) * rs * g0.y + b0.y;
  const float o2 = (v0.z - mean) * rs * g0.z + b0.z;
  const float o3 = (v0.w - mean) * rs * g0.w + b0.w;
  const float o4 = (v1.x - mean) * rs * g1.x + b1.x;
  const float o5 = (v1.y - mean) * rs * g1.y + b1.y;
  const float o6 = (v1.z - mean) * rs * g1.z + b1.z;
  const float o7 = (v1.w - mean) * rs * g1.w + b1.w;
  if constexpr (OUTF32) {
    float4* out = (float4*)outp + tok * 128;
    out[l]      = make_float4(o0, o1, o2, o3);
    out[64 + l] = make_float4(o4, o5, o6, o7);
  } else {
    s16x4 p0{(short)f2bfb(o0), (short)f2bfb(o1), (short)f2bfb(o2), (short)f2bfb(o3)};
    s16x4 p1{(short)f2bfb(o4), (short)f2bfb(o5), (short)f2bfb(o6), (short)f2bfb(o7)};
    ((s16x4*)outp)[tok * 128 + l]      = p0;
    ((s16x4*)outp)[tok * 128 + 64 + l] = p1;
  }
}

// ---------------------------------------------------------------------------
// Hydra pass1 (per M-chunk of 4 batches): qn = q/|q|; kvpart = sum (k/|k|)*v.
// ---------------------------------------------------------------------------
__global__ __launch_bounds__(256)
void hydra_pass1(const __hip_bfloat16* __restrict__ qkv,
                 __hip_bfloat16* __restrict__ qn,
                 float* __restrict__ kvpart, int b0)
{
  const int bl = blockIdx.x, ch = blockIdx.y;
  const int w = threadIdx.x >> 6, l = threadIdx.x & 63;
  float kvp[8] = {0.f, 0.f, 0.f, 0.f, 0.f, 0.f, 0.f, 0.f};
  __shared__ float part[4][512];

  for (int it = 0; it < 16; ++it) {
    const int t = ch * 64 + w * 16 + it;
    const short* row = (const short*)qkv + ((size_t)bl * TT + t) * (3 * TD);
    const s16x8 q8 = *(const s16x8*)(row + 8 * l);
    const s16x8 k8 = *(const s16x8*)(row + TD + 8 * l);
    const s16x8 v8 = *(const s16x8*)(row + 2 * TD + 8 * l);
    float qf[8], kf[8], vf[8];
    float sq = 0.f, sk = 0.f;
#pragma unroll
    for (int j = 0; j < 8; ++j) {
      qf[j] = b2f((unsigned short)q8[j]); sq += qf[j] * qf[j];
      kf[j] = b2f((unsigned short)k8[j]); sk += kf[j] * kf[j];
      vf[j] = b2f((unsigned short)v8[j]);
    }
#pragma unroll
    for (int o = 32; o > 0; o >>= 1) { sq += __shfl_xor(sq, o); sk += __shfl_xor(sk, o); }
    const float rq = rsqrtf(sq), rk = rsqrtf(sk);
    s16x8 r;
#pragma unroll
    for (int j = 0; j < 8; ++j) {
      r[j] = (short)f2bfb(qf[j] * rq);
      kvp[j] += kf[j] * rk * vf[j];
    }
    *(s16x8*)((short*)qn + ((size_t)bl * TT + t) * TD + 8 * l) = r;
  }
#pragma unroll
  for (int j = 0; j < 8; ++j) part[w][8 * l + j] = kvp[j];
  __syncthreads();
#pragma unroll
  for (int hh = 0; hh < 2; ++hh) {
    const int d = threadIdx.x + hh * 256;
    kvpart[((size_t)(b0 + bl) * 32 + ch) * TD + d]
        = part[0][d] + part[1][d] + part[2][d] + part[3][d];
  }
}

__global__ __launch_bounds__(256)
void kv_reduce(const float* __restrict__ kvpart, float* __restrict__ kv)
{
  const int i = blockIdx.x * 256 + threadIdx.x;
  const int b = i >> 9, d = i & 511;
  float s = 0.f;
#pragma unroll
  for (int ch = 0; ch < 32; ++ch) s += kvpart[((size_t)b * 32 + ch) * TD + d];
  kv[i] = s;
}

__global__ __launch_bounds__(256)
void qscale_k(__hip_bfloat16* qn, const float* __restrict__ kv)
{
  const size_t i = ((size_t)blockIdx.x * 256 + threadIdx.x) * 8;
  const size_t tok = i >> 9;
  const int d = (int)(i & 511);
  const int b = (int)(tok >> 11);
  const s16x8 v = *(const s16x8*)((const short*)qn + i);
  const float4 k0 = *(const float4*)(kv + b * 512 + d);
  const float4 k1 = *(const float4*)(kv + b * 512 + d + 4);
  s16x8 r;
  r[0] = (short)f2bfb(b2f((unsigned short)v[0]) * k0.x);
  r[1] = (short)f2bfb(b2f((unsigned short)v[1]) * k0.y);
  r[2] = (short)f2bfb(b2f((unsigned short)v[2]) * k0.z);
  r[3] = (short)f2bfb(b2f((unsigned short)v[3]) * k0.w);
  r[4] = (short)f2bfb(b2f((unsigned short)v[4]) * k1.x);
  r[5] = (short)f2bfb(b2f((unsigned short)v[5]) * k1.y);
  r[6] = (short)f2bfb(b2f((unsigned short)v[6]) * k1.z);
  r[7] = (short)f2bfb(b2f((unsigned short)v[7]) * k1.w);
  *(s16x8*)((short*)qn + i) = r;
}

__global__ __launch_bounds__(256)
void glu_k(const __hip_bfloat16* __restrict__ c, __hip_bfloat16* __restrict__ out)
{
  const size_t i = ((size_t)blockIdx.x * 256 + threadIdx.x) * 8;
  const size_t tok = i >> 9;
  const int d = (int)(i & 511);
  const short* row = (const short*)c + tok * 1024;
  const s16x8 a8 = *(const s16x8*)(row + d);
  const s16x8 g8 = *(const s16x8*)(row + 512 + d);
  s16x8 r;
#pragma unroll
  for (int j = 0; j < 8; ++j) {
    const float a = b2f((unsigned short)a8[j]);
    const float g = b2f((unsigned short)g8[j]);
    r[j] = (short)f2bfb(a * sigm(g));
  }
  *(s16x8*)((short*)out + i) = r;
}

__global__ __launch_bounds__(256)
void dwt_k(const float* __restrict__ dww, float* __restrict__ dwt)
{
  const int i = blockIdx.x * 256 + threadIdx.x;
  if (i >= KW * TD) return;
  const int j = i / TD, d = i % TD;
  dwt[i] = dww[d * KW + j];
}

// ---------------------------------------------------------------------------
// depthwise conv(K=31, pad 15) + bias + LN + swish -> bf16.
// 512 thr, 1 channel/thread, CT=16 tokens/block, 4 independent FMA chains.
// ---------------------------------------------------------------------------
__global__ __launch_bounds__(512)
void conv_ln_swish3(const __hip_bfloat16* __restrict__ gin, const float* __restrict__ dwt,
                    const float* __restrict__ dwb, const float* __restrict__ lg,
                    const float* __restrict__ lb, __hip_bfloat16* __restrict__ out)
{
  const int b  = blockIdx.x / (TT / CT);
  const int t0 = (blockIdx.x % (TT / CT)) * CT;
  const int d  = threadIdx.x;
  const int w = threadIdx.x >> 6, l = threadIdx.x & 63;

  float wreg[KW];
#pragma unroll
  for (int j = 0; j < KW; ++j) wreg[j] = dwt[j * TD + d];

  const unsigned short* base = (const unsigned short*)gin + (size_t)b * TT * TD + d;
  float xv[CT + KW - 1];
#pragma unroll
  for (int r = 0; r < CT + KW - 1; ++r) {
    const int tt = t0 + r - 15;
    xv[r] = (tt >= 0 && tt < TT) ? b2f(base[(size_t)tt * TD]) : 0.f;
  }

  const float bv = dwb[d];
  float a[CT];
#pragma unroll
  for (int t = 0; t < CT; ++t) {
    float p0 = bv, p1 = 0.f, p2 = 0.f, p3 = 0.f;
#pragma unroll
    for (int j = 0; j < 8; ++j) {
      p0 += xv[t + j] * wreg[j];
      p1 += xv[t + 8 + j] * wreg[8 + j];
      p2 += xv[t + 16 + j] * wreg[16 + j];
      if (j < 7) p3 += xv[t + 24 + j] * wreg[24 + j];
    }
    a[t] = (p0 + p1) + (p2 + p3);
  }

  __shared__ float red[2][8][CT];
#pragma unroll
  for (int t = 0; t < CT; ++t) {
    float ps = a[t], pq = a[t] * a[t];
#pragma unroll
    for (int o = 32; o > 0; o >>= 1) { ps += __shfl_xor(ps, o); pq += __shfl_xor(pq, o); }
    if (l == 0) { red[0][w][t] = ps; red[1][w][t] = pq; }
  }
  __syncthreads();
  const float gv = lg[d], bbv = lb[d];
#pragma unroll
  for (int t = 0; t < CT; ++t) {
    float s = 0.f, q = 0.f;
#pragma unroll
    for (int ww = 0; ww < 8; ++ww) { s += red[0][ww][t]; q += red[1][ww][t]; }
    const float mean = s * (1.f / TD);
    const float rs = rsqrtf(q * (1.f / TD) - mean * mean + 1e-5f);
    const float y = (a[t] - mean) * rs * gv + bbv;
    out[((size_t)b * TT + t0 + t) * TD + d] = __float2bfloat16(y * sigm(y));
  }
}

// all 8 weight casts in one dispatch (grid.y = job)
struct CastJobs {
  const float* src[8];
  __hip_bfloat16* dst[8];
  int n8[8];
};
__global__ __launch_bounds__(256)
void cast_all(CastJobs jobs)
{
  const int y = blockIdx.y;
  const int i = blockIdx.x * 256 + threadIdx.x;
  if (i >= jobs.n8[y]) return;
  const float4 a = ((const float4*)jobs.src[y])[2 * i];
  const float4 b = ((const float4*)jobs.src[y])[2 * i + 1];
  s16x8 r;
  r[0] = (short)f2bfb(a.x); r[1] = (short)f2bfb(a.y);
  r[2] = (short)f2bfb(a.z); r[3] = (short)f2bfb(a.w);
  r[4] = (short)f2bfb(b.x); r[5] = (short)f2bfb(b.y);
  r[6] = (short)f2bfb(b.z); r[7] = (short)f2bfb(b.w);
  ((s16x8*)jobs.dst[y])[i] = r;
}

extern "C" void kernel_launch(void* const* d_in, const int* in_sizes, int n_in,
                              void* d_out, int out_size, void* d_ws, size_t ws_size,
                              hipStream_t stream)
{
  const float* x      = (const float*)d_in[0];
  const float* ln1_g  = (const float*)d_in[1];
  const float* ln1_b  = (const float*)d_in[2];
  const float* ff1_w1 = (const float*)d_in[3];
  const float* ff1_b1 = (const float*)d_in[4];
  const float* ff1_w2 = (const float*)d_in[5];
  const float* ff1_b2 = (const float*)d_in[6];
  const float* lna_g  = (const float*)d_in[7];
  const float* lna_b  = (const float*)d_in[8];
  const float* qkv_w  = (const float*)d_in[9];
  const float* qkv_b  = (const float*)d_in[10];
  const float* aow    = (const float*)d_in[11];
  const float* aob    = (const float*)d_in[12];
  const float* lnc_g  = (const float*)d_in[13];
  const float* lnc_b  = (const float*)d_in[14];
  const float* pw1_w  = (const float*)d_in[15];
  const float* pw1_b  = (const float*)d_in[16];
  const float* dw_w   = (const float*)d_in[17];
  const float* dw_b   = (const float*)d_in[18];
  const float* lncn_g = (const float*)d_in[19];
  const float* lncn_b = (const float*)d_in[20];
  const float* pw2_w  = (const float*)d_in[21];
  const float* pw2_b  = (const float*)d_in[22];
  const float* ln2_g  = (const float*)d_in[23];
  const float* ln2_b  = (const float*)d_in[24];
  const float* ff2_w1 = (const float*)d_in[25];
  const float* ff2_b1 = (const float*)d_in[26];
  const float* ff2_w2 = (const float*)d_in[27];
  const float* ff2_b2 = (const float*)d_in[28];
  const float* lno_g  = (const float*)d_in[29];
  const float* lno_b  = (const float*)d_in[30];
  (void)in_sizes; (void)n_in; (void)out_size;

  float* res = (float*)d_out;

  char* ws = (char*)d_ws;
  size_t off = 0;
  auto alloc = [&](size_t bytes) {
    char* p = ws + off;
    off = (off + bytes + 255) & ~(size_t)255;
    return p;
  };

  __hip_bfloat16* wff1a = (__hip_bfloat16*)alloc((size_t)TDFF * TD * 2);
  __hip_bfloat16* wff1b = (__hip_bfloat16*)alloc((size_t)TD * TDFF * 2);
  __hip_bfloat16* wqkv  = (__hip_bfloat16*)alloc((size_t)3 * TD * TD * 2);
  __hip_bfloat16* wao   = (__hip_bfloat16*)alloc((size_t)TD * TD * 2);
  __hip_bfloat16* wpw1  = (__hip_bfloat16*)alloc((size_t)2 * TD * TD * 2);
  __hip_bfloat16* wpw2  = (__hip_bfloat16*)alloc((size_t)TD * TD * 2);
  __hip_bfloat16* wff2a = (__hip_bfloat16*)alloc((size_t)TDFF * TD * 2);
  __hip_bfloat16* wff2b = (__hip_bfloat16*)alloc((size_t)TD * TDFF * 2);
  __hip_bfloat16* h     = (__hip_bfloat16*)alloc((size_t)NTOK * TD * 2);
  __hip_bfloat16* big   = (__hip_bfloat16*)alloc((size_t)CH * TDFF * 2);
  float*          kv    = (float*)alloc((size_t)TB * TD * 4);
  float*          kvp   = (float*)alloc((size_t)TB * 32 * TD * 4);
  float*          dwt   = (float*)alloc((size_t)KW * TD * 4);

  if (ws_size < off) return;

  const dim3 blk(256), blk512(512);
  const int M = NTOK;

  CastJobs jobs;
  jobs.src[0] = ff1_w1; jobs.dst[0] = wff1a; jobs.n8[0] = TDFF * TD / 8;
  jobs.src[1] = ff1_w2; jobs.dst[1] = wff1b; jobs.n8[1] = TD * TDFF / 8;
  jobs.src[2] = qkv_w;  jobs.dst[2] = wqkv;  jobs.n8[2] = 3 * TD * TD / 8;
  jobs.src[3] = aow;    jobs.dst[3] = wao;   jobs.n8[3] = TD * TD / 8;
  jobs.src[4] = pw1_w;  jobs.dst[4] = wpw1;  jobs.n8[4] = 2 * TD * TD / 8;
  jobs.src[5] = pw2_w;  jobs.dst[5] = wpw2;  jobs.n8[5] = TD * TD / 8;
  jobs.src[6] = ff2_w1; jobs.dst[6] = wff2a; jobs.n8[6] = TDFF * TD / 8;
  jobs.src[7] = ff2_w2; jobs.dst[7] = wff2b; jobs.n8[7] = TD * TDFF / 8;
  cast_all<<<dim3((TDFF * TD / 8 + 255) / 256, 8), blk, 0, stream>>>(jobs);
  dwt_k<<<(KW * TD + 255) / 256, blk, 0, stream>>>(dw_w, dwt);

  // ---- FF1 (half-step): res = x + 0.5*ffn(ln1(x)) ----
  ln_k<0><<<M / 4, blk, 0, stream>>>(x, ln1_g, ln1_b, h);
  for (int c = 0; c < NCHUNK; ++c) {
    const size_t o5 = (size_t)c * CH * TD;
    gemm_bt<1><<<dim3(CH / 128, TDFF / 128), blk, 0, stream>>>(
        h + o5, wff1a, ff1_b1, nullptr, nullptr, big, TDFF, TD, 0.f);
    gemm_bt<2><<<dim3(CH / 128, TD / 128), blk, 0, stream>>>(
        big, wff1b, ff1_b2, x + o5, res + o5, nullptr, TD, TDFF, 0.5f);
  }

  // ---- Hydra attention ----
  ln_k<0><<<M / 4, blk, 0, stream>>>(res, lna_g, lna_b, h);
  for (int c = 0; c < NCHUNK; ++c) {
    const size_t o5 = (size_t)c * CH * TD;
    gemm_bt<0><<<dim3(CH / 128, 3 * TD / 128), blk, 0, stream>>>(
        h + o5, wqkv, qkv_b, nullptr, nullptr, big, 3 * TD, TD, 0.f);
    hydra_pass1<<<dim3(CH / TT, 32), blk, 0, stream>>>(big, h + o5, kvp, c * (CH / TT));
  }
  kv_reduce<<<(TB * TD) / 256, blk, 0, stream>>>(kvp, kv);
  qscale_k<<<(M * (TD / 8)) / 256, blk, 0, stream>>>(h, kv);
  gemm_bt<2><<<dim3(M / 128, TD / 128), blk, 0, stream>>>(
      h, wao, aob, res, res, nullptr, TD, TD, 1.f);

  // ---- Conv module ----
  ln_k<0><<<M / 4, blk, 0, stream>>>(res, lnc_g, lnc_b, h);
  for (int c = 0; c < NCHUNK; ++c) {
    const size_t o5 = (size_t)c * CH * TD;
    gemm_bt<0><<<dim3(CH / 128, 2 * TD / 128), blk, 0, stream>>>(
        h + o5, wpw1, pw1_b, nullptr, nullptr, big, 2 * TD, TD, 0.f);
    glu_k<<<(CH * (TD / 8)) / 256, blk, 0, stream>>>(big, h + o5);
  }
  conv_ln_swish3<<<TB * (TT / CT), blk512, 0, stream>>>(h, dwt, dw_b, lncn_g, lncn_b, big);
  gemm_bt<2><<<dim3(M / 128, TD / 128), blk, 0, stream>>>(
      big, wpw2, pw2_b, res, res, nullptr, TD, TD, 1.f);

  // ---- FF2 (half-step) ----
  ln_k<0><<<M / 4, blk, 0, stream>>>(res, ln2_g, ln2_b, h);
  for (int c = 0; c < NCHUNK; ++c) {
    const size_t o5 = (size_t)c * CH * TD;
    gemm_bt<1><<<dim3(CH / 128, TDFF / 128), blk, 0, stream>>>(
        h + o5, wff2a, ff2_b1, nullptr, nullptr, big, TDFF, TD, 0.f);
    gemm_bt<2><<<dim3(CH / 128, TD / 128), blk, 0, stream>>>(
        big, wff2b, ff2_b2, res + o5, res + o5, nullptr, TD, TDFF, 0.5f);
  }

  // ---- final LN (in-place on d_out) ----
  ln_k<1><<<M / 4, blk, 0, stream>>>(res, lno_g, lno_b, res);
}

// Round 7
// 1053.963 us; speedup vs baseline: 1.2437x; 1.0614x over previous
//
#include <hip/hip_runtime.h>
#include <hip/hip_bf16.h>
#include <cstdint>
#include <cstddef>

#define DEVI __device__ __forceinline__

typedef __attribute__((ext_vector_type(4))) float f32x4;
typedef __attribute__((ext_vector_type(8))) short s16x8;
typedef __attribute__((ext_vector_type(4))) short s16x4;

constexpr int TB = 16;         // batch
constexpr int TT = 2048;       // time
constexpr int TD = 512;        // model dim
constexpr int TDFF = 2048;     // ffn dim
constexpr int NTOK = TB * TT;  // 32768
constexpr int KW = 31;         // conv kernel width
constexpr int CH = 8192;       // M-chunk (4 whole batches)
constexpr int NCHUNK = NTOK / CH;
constexpr int CT = 16;         // conv: tokens per block

DEVI float b2f(unsigned short u) {
  union { float f; unsigned v; } x; x.v = ((unsigned)u) << 16; return x.f;
}
DEVI unsigned short f2bfb(float f) {
  __hip_bfloat16 h = __float2bfloat16(f);
  return __builtin_bit_cast(unsigned short, h);
}
DEVI float sigm(float x) { return 1.0f / (1.0f + __expf(-x)); }

DEVI void gload_lds16(const void* g, void* l) {
  __builtin_amdgcn_global_load_lds(
      (__attribute__((address_space(1))) unsigned int*)g,
      (__attribute__((address_space(3))) unsigned int*)l, 16, 0, 0);
}

DEVI f32x4 mfma_bf16(s16x8 a, s16x8 b, f32x4 c) {
  asm("v_mfma_f32_16x16x32_bf16 %0, %1, %2, %0" : "+v"(c) : "v"(a), "v"(b));
  return c;
}

// ---------------------------------------------------------------------------
// GEMM: C(Mrows,N) = A(.,K) x B(N,K)^T + bias  (A,B bf16 row-major)
// EPI 0: out = bf16(acc+bias)
// EPI 1: out = bf16(swish(acc+bias))
// EPI 2: resout(bf16) = resin + rscale*(acc+bias); resin f32 (RBF=0) or bf16
//        (RBF=1, may alias resout)
// 128x128 tile, BK=64, 256 thr (4 waves 2x2), global_load_lds width-16 staging.
// SWAPPED-OPERAND mfma(b,a): lane holds row = Ablk + m*16 + (l&15) fixed,
// reg r = 4 consecutive C-cols at Bblk + n*16 + (l>>4)*4 -> vectorized stores.
// ---------------------------------------------------------------------------
template<int EPI, int RBF>
__global__ __launch_bounds__(256)
void gemm_bt(const __hip_bfloat16* __restrict__ A, const __hip_bfloat16* __restrict__ Bw,
             const float* __restrict__ bias, const void* resin,
             __hip_bfloat16* resout, __hip_bfloat16* __restrict__ outbf,
             int N, int K, float rscale)
{
  __shared__ alignas(16) short lds[2 * 128 * 64];
  short* As = lds;
  short* Bs = lds + 128 * 64;

  const int tid = threadIdx.x;
  const int w = tid >> 6, l = tid & 63;
  const int row0 = blockIdx.x * 128;
  const int col0 = blockIdx.y * 128;

  const int srow = w * 8 + (l >> 3);
  const int scol = (l & 7) * 8;

  f32x4 acc[4][4];
#pragma unroll
  for (int m = 0; m < 4; ++m)
#pragma unroll
    for (int n = 0; n < 4; ++n)
      acc[m][n] = f32x4{0.f, 0.f, 0.f, 0.f};

  const int wr = (w >> 1) * 64, wc = (w & 1) * 64;

  for (int k0 = 0; k0 < K; k0 += 64) {
    __syncthreads();
#pragma unroll
    for (int it = 0; it < 4; ++it) {
      gload_lds16(A  + (size_t)(row0 + it * 32 + srow) * K + k0 + scol,
                  (char*)As + (it * 32 + w * 8) * 128);
      gload_lds16(Bw + (size_t)(col0 + it * 32 + srow) * K + k0 + scol,
                  (char*)Bs + (it * 32 + w * 8) * 128);
    }
    __syncthreads();
#pragma unroll
    for (int ks = 0; ks < 2; ++ks) {
      const int ko = ks * 64 + (l >> 4) * 16;
      s16x8 af[4], bfr[4];
#pragma unroll
      for (int m = 0; m < 4; ++m)
        af[m] = *(const s16x8*)((const char*)As + (wr + m * 16 + (l & 15)) * 128 + ko);
#pragma unroll
      for (int n = 0; n < 4; ++n)
        bfr[n] = *(const s16x8*)((const char*)Bs + (wc + n * 16 + (l & 15)) * 128 + ko);
#pragma unroll
      for (int m = 0; m < 4; ++m)
#pragma unroll
        for (int n = 0; n < 4; ++n)
          acc[m][n] = mfma_bf16(bfr[n], af[m], acc[m][n]);   // swapped: row-major frag
    }
  }

  asm volatile("s_nop 7\n\ts_nop 7");

#pragma unroll
  for (int m = 0; m < 4; ++m) {
    const int grow = row0 + wr + m * 16 + (l & 15);
#pragma unroll
    for (int n = 0; n < 4; ++n) {
      const int gcol0 = col0 + wc + n * 16 + (l >> 4) * 4;
      const size_t idx = (size_t)grow * N + gcol0;
      const float4 bv = *(const float4*)(bias + gcol0);
      float vx = acc[m][n][0] + bv.x;
      float vy = acc[m][n][1] + bv.y;
      float vz = acc[m][n][2] + bv.z;
      float vw = acc[m][n][3] + bv.w;
      if constexpr (EPI == 0) {
        s16x4 p{(short)f2bfb(vx), (short)f2bfb(vy), (short)f2bfb(vz), (short)f2bfb(vw)};
        *(s16x4*)(outbf + idx) = p;
      } else if constexpr (EPI == 1) {
        vx *= sigm(vx); vy *= sigm(vy); vz *= sigm(vz); vw *= sigm(vw);
        s16x4 p{(short)f2bfb(vx), (short)f2bfb(vy), (short)f2bfb(vz), (short)f2bfb(vw)};
        *(s16x4*)(outbf + idx) = p;
      } else {
        float r0, r1, r2, r3;
        if constexpr (RBF) {
          const s16x4 rv = *(const s16x4*)((const short*)resin + idx);
          r0 = b2f((unsigned short)rv[0]); r1 = b2f((unsigned short)rv[1]);
          r2 = b2f((unsigned short)rv[2]); r3 = b2f((unsigned short)rv[3]);
        } else {
          const float4 rv = *(const float4*)((const float*)resin + idx);
          r0 = rv.x; r1 = rv.y; r2 = rv.z; r3 = rv.w;
        }
        s16x4 p{(short)f2bfb(r0 + rscale * vx), (short)f2bfb(r1 + rscale * vy),
                (short)f2bfb(r2 + rscale * vz), (short)f2bfb(r3 + rscale * vw)};
        *(s16x4*)(resout + idx) = p;
      }
    }
  }
}

// ---------------------------------------------------------------------------
// gemm_bt64: same structure, 128x64 tile (for K=2048 N=512 GEMMs; doubles
// blocks/CU from 1 to 2+ so memory phases overlap across blocks).
// ---------------------------------------------------------------------------
template<int EPI, int RBF>
__global__ __launch_bounds__(256)
void gemm_bt64(const __hip_bfloat16* __restrict__ A, const __hip_bfloat16* __restrict__ Bw,
               const float* __restrict__ bias, const void* resin,
               __hip_bfloat16* resout, __hip_bfloat16* __restrict__ outbf,
               int N, int K, float rscale)
{
  __shared__ alignas(16) short lds[192 * 64];   // A 128 rows + B 64 rows
  short* As = lds;
  short* Bs = lds + 128 * 64;

  const int tid = threadIdx.x;
  const int w = tid >> 6, l = tid & 63;
  const int row0 = blockIdx.x * 128;
  const int col0 = blockIdx.y * 64;

  const int srow = w * 8 + (l >> 3);
  const int scol = (l & 7) * 8;

  f32x4 acc[4][2];
#pragma unroll
  for (int m = 0; m < 4; ++m)
#pragma unroll
    for (int n = 0; n < 2; ++n)
      acc[m][n] = f32x4{0.f, 0.f, 0.f, 0.f};

  const int wr = (w >> 1) * 64, wc = (w & 1) * 32;

  for (int k0 = 0; k0 < K; k0 += 64) {
    __syncthreads();
#pragma unroll
    for (int it = 0; it < 4; ++it)
      gload_lds16(A + (size_t)(row0 + it * 32 + srow) * K + k0 + scol,
                  (char*)As + (it * 32 + w * 8) * 128);
#pragma unroll
    for (int it = 0; it < 2; ++it)
      gload_lds16(Bw + (size_t)(col0 + it * 32 + srow) * K + k0 + scol,
                  (char*)Bs + (it * 32 + w * 8) * 128);
    __syncthreads();
#pragma unroll
    for (int ks = 0; ks < 2; ++ks) {
      const int ko = ks * 64 + (l >> 4) * 16;
      s16x8 af[4], bfr[2];
#pragma unroll
      for (int m = 0; m < 4; ++m)
        af[m] = *(const s16x8*)((const char*)As + (wr + m * 16 + (l & 15)) * 128 + ko);
#pragma unroll
      for (int n = 0; n < 2; ++n)
        bfr[n] = *(const s16x8*)((const char*)Bs + (wc + n * 16 + (l & 15)) * 128 + ko);
#pragma unroll
      for (int m = 0; m < 4; ++m)
#pragma unroll
        for (int n = 0; n < 2; ++n)
          acc[m][n] = mfma_bf16(bfr[n], af[m], acc[m][n]);
    }
  }

  asm volatile("s_nop 7\n\ts_nop 7");

#pragma unroll
  for (int m = 0; m < 4; ++m) {
    const int grow = row0 + wr + m * 16 + (l & 15);
#pragma unroll
    for (int n = 0; n < 2; ++n) {
      const int gcol0 = col0 + wc + n * 16 + (l >> 4) * 4;
      const size_t idx = (size_t)grow * N + gcol0;
      const float4 bv = *(const float4*)(bias + gcol0);
      float vx = acc[m][n][0] + bv.x;
      float vy = acc[m][n][1] + bv.y;
      float vz = acc[m][n][2] + bv.z;
      float vw = acc[m][n][3] + bv.w;
      if constexpr (EPI == 0) {
        s16x4 p{(short)f2bfb(vx), (short)f2bfb(vy), (short)f2bfb(vz), (short)f2bfb(vw)};
        *(s16x4*)(outbf + idx) = p;
      } else if constexpr (EPI == 1) {
        vx *= sigm(vx); vy *= sigm(vy); vz *= sigm(vz); vw *= sigm(vw);
        s16x4 p{(short)f2bfb(vx), (short)f2bfb(vy), (short)f2bfb(vz), (short)f2bfb(vw)};
        *(s16x4*)(outbf + idx) = p;
      } else {
        float r0, r1, r2, r3;
        if constexpr (RBF) {
          const s16x4 rv = *(const s16x4*)((const short*)resin + idx);
          r0 = b2f((unsigned short)rv[0]); r1 = b2f((unsigned short)rv[1]);
          r2 = b2f((unsigned short)rv[2]); r3 = b2f((unsigned short)rv[3]);
        } else {
          const float4 rv = *(const float4*)((const float*)resin + idx);
          r0 = rv.x; r1 = rv.y; r2 = rv.z; r3 = rv.w;
        }
        s16x4 p{(short)f2bfb(r0 + rscale * vx), (short)f2bfb(r1 + rscale * vy),
                (short)f2bfb(r2 + rscale * vz), (short)f2bfb(r3 + rscale * vw)};
        *(s16x4*)(resout + idx) = p;
      }
    }
  }
}

// ---------------------------------------------------------------------------
// LayerNorm over D=512. One wave per token, 4 tokens/block.
// INBF: input bf16 (else f32). OUTF32: output f32 (else bf16).
// ---------------------------------------------------------------------------
template<int OUTF32, int INBF>
__global__ __launch_bounds__(256)
void ln_k(const void* __restrict__ xp, const float* __restrict__ g,
          const float* __restrict__ b, void* __restrict__ outp)
{
  const int w = threadIdx.x >> 6, l = threadIdx.x & 63;
  const size_t tok = (size_t)blockIdx.x * 4 + w;
  float v[8];
  if constexpr (INBF) {
    const s16x8 xv = ((const s16x8*)xp)[tok * 64 + l];
#pragma unroll
    for (int j = 0; j < 8; ++j) v[j] = b2f((unsigned short)xv[j]);
  } else {
    const float4* xr = (const float4*)xp + tok * 128;
    const float4 a = xr[2 * l], c = xr[2 * l + 1];
    v[0] = a.x; v[1] = a.y; v[2] = a.z; v[3] = a.w;
    v[4] = c.x; v[5] = c.y; v[6] = c.z; v[7] = c.w;
  }
  float s = 0.f, q = 0.f;
#pragma unroll
  for (int j = 0; j < 8; ++j) { s += v[j]; q += v[j] * v[j]; }
#pragma unroll
  for (int o = 32; o > 0; o >>= 1) { s += __shfl_xor(s, o); q += __shfl_xor(q, o); }
  const float mean = s * (1.f / TD);
  const float rs = rsqrtf(q * (1.f / TD) - mean * mean + 1e-5f);
  const float4 g0 = ((const float4*)g)[2 * l], g1 = ((const float4*)g)[2 * l + 1];
  const float4 b0 = ((const float4*)b)[2 * l], b1 = ((const float4*)b)[2 * l + 1];
  const float gg[8] = {g0.x, g0.y, g0.z, g0.w, g1.x, g1.y, g1.z, g1.w};
  const float bb[8] = {b0.x, b0.y, b0.z, b0.w, b1.x, b1.y, b1.z, b1.w};
  float o8[8];
#pragma unroll
  for (int j = 0; j < 8; ++j) o8[j] = (v[j] - mean) * rs * gg[j] + bb[j];
  if constexpr (OUTF32) {
    float4* out = (float4*)outp + tok * 128;
    out[2 * l]     = make_float4(o8[0], o8[1], o8[2], o8[3]);
    out[2 * l + 1] = make_float4(o8[4], o8[5], o8[6], o8[7]);
  } else {
    s16x8 p;
#pragma unroll
    for (int j = 0; j < 8; ++j) p[j] = (short)f2bfb(o8[j]);
    ((s16x8*)outp)[tok * 64 + l] = p;
  }
}

// ---------------------------------------------------------------------------
// Hydra pass1 (per M-chunk of 4 batches): qn = q/|q|; kvpart = sum (k/|k|)*v.
// ---------------------------------------------------------------------------
__global__ __launch_bounds__(256)
void hydra_pass1(const __hip_bfloat16* __restrict__ qkv,
                 __hip_bfloat16* __restrict__ qn,
                 float* __restrict__ kvpart, int b0)
{
  const int bl = blockIdx.x, ch = blockIdx.y;
  const int w = threadIdx.x >> 6, l = threadIdx.x & 63;
  float kvp[8] = {0.f, 0.f, 0.f, 0.f, 0.f, 0.f, 0.f, 0.f};
  __shared__ float part[4][512];

  for (int it = 0; it < 16; ++it) {
    const int t = ch * 64 + w * 16 + it;
    const short* row = (const short*)qkv + ((size_t)bl * TT + t) * (3 * TD);
    const s16x8 q8 = *(const s16x8*)(row + 8 * l);
    const s16x8 k8 = *(const s16x8*)(row + TD + 8 * l);
    const s16x8 v8 = *(const s16x8*)(row + 2 * TD + 8 * l);
    float qf[8], kf[8], vf[8];
    float sq = 0.f, sk = 0.f;
#pragma unroll
    for (int j = 0; j < 8; ++j) {
      qf[j] = b2f((unsigned short)q8[j]); sq += qf[j] * qf[j];
      kf[j] = b2f((unsigned short)k8[j]); sk += kf[j] * kf[j];
      vf[j] = b2f((unsigned short)v8[j]);
    }
#pragma unroll
    for (int o = 32; o > 0; o >>= 1) { sq += __shfl_xor(sq, o); sk += __shfl_xor(sk, o); }
    const float rq = rsqrtf(sq), rk = rsqrtf(sk);
    s16x8 r;
#pragma unroll
    for (int j = 0; j < 8; ++j) {
      r[j] = (short)f2bfb(qf[j] * rq);
      kvp[j] += kf[j] * rk * vf[j];
    }
    *(s16x8*)((short*)qn + ((size_t)bl * TT + t) * TD + 8 * l) = r;
  }
#pragma unroll
  for (int j = 0; j < 8; ++j) part[w][8 * l + j] = kvp[j];
  __syncthreads();
#pragma unroll
  for (int hh = 0; hh < 2; ++hh) {
    const int d = threadIdx.x + hh * 256;
    kvpart[((size_t)(b0 + bl) * 32 + ch) * TD + d]
        = part[0][d] + part[1][d] + part[2][d] + part[3][d];
  }
}

__global__ __launch_bounds__(256)
void kv_reduce(const float* __restrict__ kvpart, float* __restrict__ kv)
{
  const int i = blockIdx.x * 256 + threadIdx.x;
  const int b = i >> 9, d = i & 511;
  float s = 0.f;
#pragma unroll
  for (int ch = 0; ch < 32; ++ch) s += kvpart[((size_t)b * 32 + ch) * TD + d];
  kv[i] = s;
}

__global__ __launch_bounds__(256)
void qscale_k(__hip_bfloat16* qn, const float* __restrict__ kv)
{
  const size_t i = ((size_t)blockIdx.x * 256 + threadIdx.x) * 8;
  const size_t tok = i >> 9;
  const int d = (int)(i & 511);
  const int b = (int)(tok >> 11);
  const s16x8 v = *(const s16x8*)((const short*)qn + i);
  const float4 k0 = *(const float4*)(kv + b * 512 + d);
  const float4 k1 = *(const float4*)(kv + b * 512 + d + 4);
  s16x8 r;
  r[0] = (short)f2bfb(b2f((unsigned short)v[0]) * k0.x);
  r[1] = (short)f2bfb(b2f((unsigned short)v[1]) * k0.y);
  r[2] = (short)f2bfb(b2f((unsigned short)v[2]) * k0.z);
  r[3] = (short)f2bfb(b2f((unsigned short)v[3]) * k0.w);
  r[4] = (short)f2bfb(b2f((unsigned short)v[4]) * k1.x);
  r[5] = (short)f2bfb(b2f((unsigned short)v[5]) * k1.y);
  r[6] = (short)f2bfb(b2f((unsigned short)v[6]) * k1.z);
  r[7] = (short)f2bfb(b2f((unsigned short)v[7]) * k1.w);
  *(s16x8*)((short*)qn + i) = r;
}

__global__ __launch_bounds__(256)
void glu_k(const __hip_bfloat16* __restrict__ c, __hip_bfloat16* __restrict__ out)
{
  const size_t i = ((size_t)blockIdx.x * 256 + threadIdx.x) * 8;
  const size_t tok = i >> 9;
  const int d = (int)(i & 511);
  const short* row = (const short*)c + tok * 1024;
  const s16x8 a8 = *(const s16x8*)(row + d);
  const s16x8 g8 = *(const s16x8*)(row + 512 + d);
  s16x8 r;
#pragma unroll
  for (int j = 0; j < 8; ++j) {
    const float a = b2f((unsigned short)a8[j]);
    const float g = b2f((unsigned short)g8[j]);
    r[j] = (short)f2bfb(a * sigm(g));
  }
  *(s16x8*)((short*)out + i) = r;
}

__global__ __launch_bounds__(256)
void dwt_k(const float* __restrict__ dww, float* __restrict__ dwt)
{
  const int i = blockIdx.x * 256 + threadIdx.x;
  if (i >= KW * TD) return;
  const int j = i / TD, d = i % TD;
  dwt[i] = dww[d * KW + j];
}

// depthwise conv + bias + LN + swish (512 thr, 1 ch/thread, CT tokens, 4 chains)
__global__ __launch_bounds__(512)
void conv_ln_swish3(const __hip_bfloat16* __restrict__ gin, const float* __restrict__ dwt,
                    const float* __restrict__ dwb, const float* __restrict__ lg,
                    const float* __restrict__ lb, __hip_bfloat16* __restrict__ out)
{
  const int b  = blockIdx.x / (TT / CT);
  const int t0 = (blockIdx.x % (TT / CT)) * CT;
  const int d  = threadIdx.x;
  const int w = threadIdx.x >> 6, l = threadIdx.x & 63;

  float wreg[KW];
#pragma unroll
  for (int j = 0; j < KW; ++j) wreg[j] = dwt[j * TD + d];

  const unsigned short* base = (const unsigned short*)gin + (size_t)b * TT * TD + d;
  float xv[CT + KW - 1];
#pragma unroll
  for (int r = 0; r < CT + KW - 1; ++r) {
    const int tt = t0 + r - 15;
    xv[r] = (tt >= 0 && tt < TT) ? b2f(base[(size_t)tt * TD]) : 0.f;
  }

  const float bv = dwb[d];
  float a[CT];
#pragma unroll
  for (int t = 0; t < CT; ++t) {
    float p0 = bv, p1 = 0.f, p2 = 0.f, p3 = 0.f;
#pragma unroll
    for (int j = 0; j < 8; ++j) {
      p0 += xv[t + j] * wreg[j];
      p1 += xv[t + 8 + j] * wreg[8 + j];
      p2 += xv[t + 16 + j] * wreg[16 + j];
      if (j < 7) p3 += xv[t + 24 + j] * wreg[24 + j];
    }
    a[t] = (p0 + p1) + (p2 + p3);
  }

  __shared__ float red[2][8][CT];
#pragma unroll
  for (int t = 0; t < CT; ++t) {
    float ps = a[t], pq = a[t] * a[t];
#pragma unroll
    for (int o = 32; o > 0; o >>= 1) { ps += __shfl_xor(ps, o); pq += __shfl_xor(pq, o); }
    if (l == 0) { red[0][w][t] = ps; red[1][w][t] = pq; }
  }
  __syncthreads();
  const float gv = lg[d], bbv = lb[d];
#pragma unroll
  for (int t = 0; t < CT; ++t) {
    float s = 0.f, q = 0.f;
#pragma unroll
    for (int ww = 0; ww < 8; ++ww) { s += red[0][ww][t]; q += red[1][ww][t]; }
    const float mean = s * (1.f / TD);
    const float rs = rsqrtf(q * (1.f / TD) - mean * mean + 1e-5f);
    const float y = (a[t] - mean) * rs * gv + bbv;
    out[((size_t)b * TT + t0 + t) * TD + d] = __float2bfloat16(y * sigm(y));
  }
}

// all 8 weight casts in one dispatch (grid.y = job)
struct CastJobs {
  const float* src[8];
  __hip_bfloat16* dst[8];
  int n8[8];
};
__global__ __launch_bounds__(256)
void cast_all(CastJobs jobs)
{
  const int y = blockIdx.y;
  const int i = blockIdx.x * 256 + threadIdx.x;
  if (i >= jobs.n8[y]) return;
  const float4 a = ((const float4*)jobs.src[y])[2 * i];
  const float4 b = ((const float4*)jobs.src[y])[2 * i + 1];
  s16x8 r;
  r[0] = (short)f2bfb(a.x); r[1] = (short)f2bfb(a.y);
  r[2] = (short)f2bfb(a.z); r[3] = (short)f2bfb(a.w);
  r[4] = (short)f2bfb(b.x); r[5] = (short)f2bfb(b.y);
  r[6] = (short)f2bfb(b.z); r[7] = (short)f2bfb(b.w);
  ((s16x8*)jobs.dst[y])[i] = r;
}

extern "C" void kernel_launch(void* const* d_in, const int* in_sizes, int n_in,
                              void* d_out, int out_size, void* d_ws, size_t ws_size,
                              hipStream_t stream)
{
  const float* x      = (const float*)d_in[0];
  const float* ln1_g  = (const float*)d_in[1];
  const float* ln1_b  = (const float*)d_in[2];
  const float* ff1_w1 = (const float*)d_in[3];
  const float* ff1_b1 = (const float*)d_in[4];
  const float* ff1_w2 = (const float*)d_in[5];
  const float* ff1_b2 = (const float*)d_in[6];
  const float* lna_g  = (const float*)d_in[7];
  const float* lna_b  = (const float*)d_in[8];
  const float* qkv_w  = (const float*)d_in[9];
  const float* qkv_b  = (const float*)d_in[10];
  const float* aow    = (const float*)d_in[11];
  const float* aob    = (const float*)d_in[12];
  const float* lnc_g  = (const float*)d_in[13];
  const float* lnc_b  = (const float*)d_in[14];
  const float* pw1_w  = (const float*)d_in[15];
  const float* pw1_b  = (const float*)d_in[16];
  const float* dw_w   = (const float*)d_in[17];
  const float* dw_b   = (const float*)d_in[18];
  const float* lncn_g = (const float*)d_in[19];
  const float* lncn_b = (const float*)d_in[20];
  const float* pw2_w  = (const float*)d_in[21];
  const float* pw2_b  = (const float*)d_in[22];
  const float* ln2_g  = (const float*)d_in[23];
  const float* ln2_b  = (const float*)d_in[24];
  const float* ff2_w1 = (const float*)d_in[25];
  const float* ff2_b1 = (const float*)d_in[26];
  const float* ff2_w2 = (const float*)d_in[27];
  const float* ff2_b2 = (const float*)d_in[28];
  const float* lno_g  = (const float*)d_in[29];
  const float* lno_b  = (const float*)d_in[30];
  (void)in_sizes; (void)n_in; (void)out_size;

  char* ws = (char*)d_ws;
  size_t off = 0;
  auto alloc = [&](size_t bytes) {
    char* p = ws + off;
    off = (off + bytes + 255) & ~(size_t)255;
    return p;
  };

  __hip_bfloat16* wff1a = (__hip_bfloat16*)alloc((size_t)TDFF * TD * 2);
  __hip_bfloat16* wff1b = (__hip_bfloat16*)alloc((size_t)TD * TDFF * 2);
  __hip_bfloat16* wqkv  = (__hip_bfloat16*)alloc((size_t)3 * TD * TD * 2);
  __hip_bfloat16* wao   = (__hip_bfloat16*)alloc((size_t)TD * TD * 2);
  __hip_bfloat16* wpw1  = (__hip_bfloat16*)alloc((size_t)2 * TD * TD * 2);
  __hip_bfloat16* wpw2  = (__hip_bfloat16*)alloc((size_t)TD * TD * 2);
  __hip_bfloat16* wff2a = (__hip_bfloat16*)alloc((size_t)TDFF * TD * 2);
  __hip_bfloat16* wff2b = (__hip_bfloat16*)alloc((size_t)TD * TDFF * 2);
  __hip_bfloat16* h     = (__hip_bfloat16*)alloc((size_t)NTOK * TD * 2);   // 32MB
  __hip_bfloat16* big   = (__hip_bfloat16*)alloc((size_t)CH * TDFF * 2);   // 32MB
  __hip_bfloat16* resb  = (__hip_bfloat16*)alloc((size_t)NTOK * TD * 2);   // 32MB bf16 residual
  float*          kv    = (float*)alloc((size_t)TB * TD * 4);
  float*          kvp   = (float*)alloc((size_t)TB * 32 * TD * 4);
  float*          dwt   = (float*)alloc((size_t)KW * TD * 4);

  if (ws_size < off) return;   // interpretable failure instead of a page fault

  const dim3 blk(256), blk512(512);
  const int M = NTOK;

  CastJobs jobs;
  jobs.src[0] = ff1_w1; jobs.dst[0] = wff1a; jobs.n8[0] = TDFF * TD / 8;
  jobs.src[1] = ff1_w2; jobs.dst[1] = wff1b; jobs.n8[1] = TD * TDFF / 8;
  jobs.src[2] = qkv_w;  jobs.dst[2] = wqkv;  jobs.n8[2] = 3 * TD * TD / 8;
  jobs.src[3] = aow;    jobs.dst[3] = wao;   jobs.n8[3] = TD * TD / 8;
  jobs.src[4] = pw1_w;  jobs.dst[4] = wpw1;  jobs.n8[4] = 2 * TD * TD / 8;
  jobs.src[5] = pw2_w;  jobs.dst[5] = wpw2;  jobs.n8[5] = TD * TD / 8;
  jobs.src[6] = ff2_w1; jobs.dst[6] = wff2a; jobs.n8[6] = TDFF * TD / 8;
  jobs.src[7] = ff2_w2; jobs.dst[7] = wff2b; jobs.n8[7] = TD * TDFF / 8;
  cast_all<<<dim3((TDFF * TD / 8 + 255) / 256, 8), blk, 0, stream>>>(jobs);
  dwt_k<<<(KW * TD + 255) / 256, blk, 0, stream>>>(dw_w, dwt);

  // ---- FF1 (half-step): resb = bf16(x + 0.5*ffn(ln1(x))) ----
  ln_k<0, 0><<<M / 4, blk, 0, stream>>>(x, ln1_g, ln1_b, h);
  for (int c = 0; c < NCHUNK; ++c) {
    const size_t o5 = (size_t)c * CH * TD;
    gemm_bt<1, 0><<<dim3(CH / 128, TDFF / 128), blk, 0, stream>>>(
        h + o5, wff1a, ff1_b1, nullptr, nullptr, big, TDFF, TD, 0.f);
    gemm_bt64<2, 0><<<dim3(CH / 128, TD / 64), blk, 0, stream>>>(
        big, wff1b, ff1_b2, x + o5, resb + o5, nullptr, TD, TDFF, 0.5f);
  }

  // ---- Hydra attention ----
  ln_k<0, 1><<<M / 4, blk, 0, stream>>>(resb, lna_g, lna_b, h);
  for (int c = 0; c < NCHUNK; ++c) {
    const size_t o5 = (size_t)c * CH * TD;
    gemm_bt<0, 0><<<dim3(CH / 128, 3 * TD / 128), blk, 0, stream>>>(
        h + o5, wqkv, qkv_b, nullptr, nullptr, big, 3 * TD, TD, 0.f);
    hydra_pass1<<<dim3(CH / TT, 32), blk, 0, stream>>>(big, h + o5, kvp, c * (CH / TT));
  }
  kv_reduce<<<(TB * TD) / 256, blk, 0, stream>>>(kvp, kv);
  qscale_k<<<(M * (TD / 8)) / 256, blk, 0, stream>>>(h, kv);
  gemm_bt<2, 1><<<dim3(M / 128, TD / 128), blk, 0, stream>>>(
      h, wao, aob, resb, resb, nullptr, TD, TD, 1.f);

  // ---- Conv module ----
  ln_k<0, 1><<<M / 4, blk, 0, stream>>>(resb, lnc_g, lnc_b, h);
  for (int c = 0; c < NCHUNK; ++c) {
    const size_t o5 = (size_t)c * CH * TD;
    gemm_bt<0, 0><<<dim3(CH / 128, 2 * TD / 128), blk, 0, stream>>>(
        h + o5, wpw1, pw1_b, nullptr, nullptr, big, 2 * TD, TD, 0.f);
    glu_k<<<(CH * (TD / 8)) / 256, blk, 0, stream>>>(big, h + o5);
  }
  conv_ln_swish3<<<TB * (TT / CT), blk512, 0, stream>>>(h, dwt, dw_b, lncn_g, lncn_b, big);
  gemm_bt<2, 1><<<dim3(M / 128, TD / 128), blk, 0, stream>>>(
      big, wpw2, pw2_b, resb, resb, nullptr, TD, TD, 1.f);

  // ---- FF2 (half-step) ----
  ln_k<0, 1><<<M / 4, blk, 0, stream>>>(resb, ln2_g, ln2_b, h);
  for (int c = 0; c < NCHUNK; ++c) {
    const size_t o5 = (size_t)c * CH * TD;
    gemm_bt<1, 0><<<dim3(CH / 128, TDFF / 128), blk, 0, stream>>>(
        h + o5, wff2a, ff2_b1, nullptr, nullptr, big, TDFF, TD, 0.f);
    gemm_bt64<2, 1><<<dim3(CH / 128, TD / 64), blk, 0, stream>>>(
        big, wff2b, ff2_b2, resb + o5, resb + o5, nullptr, TD, TDFF, 0.5f);
  }

  // ---- final LN: d_out(f32) = ln(resb) ----
  ln_k<1, 1><<<M / 4, blk, 0, stream>>>(resb, lno_g, lno_b, d_out);
}